// Round 3
// baseline (412.983 us; speedup 1.0000x reference)
//
#include <hip/hip_runtime.h>
#include <hip/hip_bf16.h>
#include <math.h>

// Shapes fixed by setup_inputs: B=1024, N=200000, D=128, K=5
#define D128 128
#define TOPK 5
#define NP 200704        // N padded to 64
#define NCH2 12544       // NP/16 : 16-key chunks
#define NSTRIP 392       // NP/512 strips (pass-A block x-dim)
#define MARGIN 0.008f    // bf16-sim (<=3.9e-3) + fp16-storage (<=4.9e-4) + slack
#define CAP 1024         // candidate-chunk capacity per query (overflow -> full scan)
#define SCAP 96          // candidate-strip capacity per query (overflow -> full scan)
#define SCST 44          // sC row stride in shorts (22 dwords, gcd(22,32)=2: conflict-free b16)

typedef __attribute__((ext_vector_type(8))) short short8;   // 8 bf16 = 4 VGPR
typedef __attribute__((ext_vector_type(4))) short s4v;      // 4 shorts = 8 B
typedef __attribute__((ext_vector_type(4))) float f32x4;    // MFMA acc

__device__ __forceinline__ short f2bf(float f) {
    union { float f; unsigned u; } c; c.f = f;
    unsigned u = c.u + 0x7FFFu + ((c.u >> 16) & 1u);
    return (short)(u >> 16);
}

// packed fp32x2 -> bf16x2 (RNE); compiler emits v_cvt_pk_bf16_f32
__device__ __forceinline__ unsigned pkbf(float x, float y) {
    __hip_bfloat162 h = __float22bfloat162_rn(make_float2(x, y));
    unsigned u; __builtin_memcpy(&u, &h, 4);
    return u;
}

// Guarded branch-free descending insert (val+idx). Precondition: nv > v[NN-1].
template <int NN>
__device__ __forceinline__ void insertg(float (&v)[NN], int (&x)[NN], float nv, int nj) {
    bool g[NN];
    #pragma unroll
    for (int i = 0; i < NN; ++i) g[i] = nv > v[i];
    #pragma unroll
    for (int i = NN - 1; i > 0; --i) {
        v[i] = g[i - 1] ? v[i - 1] : (g[i] ? nv : v[i]);
        x[i] = g[i - 1] ? x[i - 1] : (g[i] ? nj : x[i]);
    }
    v[0] = g[0] ? nv : v[0];
    x[0] = g[0] ? nj : x[0];
}
// Values-only variant. Precondition: nv > v[NN-1].
template <int NN>
__device__ __forceinline__ void insertv(float (&v)[NN], float nv) {
    bool g[NN];
    #pragma unroll
    for (int i = 0; i < NN; ++i) g[i] = nv > v[i];
    #pragma unroll
    for (int i = NN - 1; i > 0; --i)
        v[i] = g[i - 1] ? v[i - 1] : (g[i] ? nv : v[i]);
    v[0] = g[0] ? nv : v[0];
}

// ---------------- Kernel A: normalize queries -> fp32 qn + bf16 qbf ----------------
__global__ void qnorm_kernel(const float* __restrict__ q, float* __restrict__ qn,
                             short* __restrict__ qbf) {
    int b = blockIdx.x, t = threadIdx.x;   // 64 threads
    float v0 = q[(size_t)b * D128 + t];
    float v1 = q[(size_t)b * D128 + t + 64];
    float ss = v0 * v0 + v1 * v1;
    #pragma unroll
    for (int off = 32; off > 0; off >>= 1) ss += __shfl_xor(ss, off, 64);
    float scale = 1.0f / fmaxf(sqrtf(ss), 1e-12f);
    float a0 = v0 * scale, a1 = v1 * scale;
    qn[(size_t)b * D128 + t] = a0;
    qn[(size_t)b * D128 + t + 64] = a1;
    qbf[(size_t)b * D128 + t] = f2bf(a0);
    qbf[(size_t)b * D128 + t + 64] = f2bf(a1);
}

#define MFMA16(a, b, c) __builtin_amdgcn_mfma_f32_16x16x32_bf16(a, b, c, 0, 0, 0)

// ---------------- Kernel B: MFMA sweep (fused fp32->bf16 staging) ----------------
// 1D grid of 1568 blocks, XCD-swizzled: strip = (b&7)+8*(b>>5), qsg = (b>>3)&3.
// The 4 qsg-blocks of one strip get consecutive dispatch slots on the SAME XCD
// (ids differ by 8 -> same XCD under round-robin), so 3 of 4 strip reads are L2 hits.
// Block = 4 waves x 64 queries = 256 queries x one 512-key strip (8 rounds of 64 keys,
// each round = 4 MFMA tiles = 4 chunks). Reads fp32 memory directly: register-prefetch
// pipeline (distance 2) holds 8 float4, converts to bf16 at LDS-write time.
// Cross-quad chunk-max reduce: XOR-select network + 3-shuffle butterfly (was 8 shfl).
__global__ __launch_bounds__(256, 4) void simtopk_max(
    const short* __restrict__ qbf, const float* __restrict__ mem,
    _Float16* __restrict__ candT, _Float16* __restrict__ stripT, int N) {
    __shared__ short sK[64 * 136];        // 17.4 KB key tile (272B stride)
    __shared__ _Float16 sC[256 * SCST];   // 22.5 KB chunk-max tile (32 used of 44)
    const int b = blockIdx.x;
    const int strip = (b & 7) + ((b >> 5) << 3);   // 0..391
    const int qsg = (b >> 3) & 3;                  // 0..3
    const int t = threadIdx.x, w = t >> 6, lane = t & 63;
    const int n = lane & 15, quad = lane >> 4;
    const bool qb0 = (quad & 1) != 0, qb1 = (quad & 2) != 0;
    const int qbase = qsg * 256 + w * 64;

    // Resident B-frags: 4 q-tiles x 4 K-steps (64 VGPR)
    short8 bq[4][4];
    #pragma unroll
    for (int f = 0; f < 4; ++f) {
        const short* qrow = qbf + (size_t)(qbase + f * 16 + n) * D128 + quad * 8;
        #pragma unroll
        for (int s = 0; s < 4; ++s) bq[f][s] = *(const short8*)(qrow + s * 32);
    }

    const size_t k0 = (size_t)strip * 512;
    const int srow = t >> 4, scol = t & 15;
    const float* gbase = mem + (k0 + srow) * (size_t)D128 + scol * 8;
    const bool tail = (k0 + 512 > (size_t)N);   // strips 390,391 contain padding rows

    float4 fa[8];   // prefetched fp32 group: 4 rows x 8 floats

    auto loadg = [&](int g) {
        const float* base = gbase + (size_t)g * 64 * D128;
        #pragma unroll
        for (int i = 0; i < 4; ++i) {
            const float4* p = (const float4*)(base + (size_t)i * 16 * D128);
            if (tail) {
                size_t key = k0 + (size_t)(g * 64 + srow + i * 16);
                if (key >= (size_t)N) p = (const float4*)mem;   // safe dummy row
            }
            fa[2 * i]     = p[0];
            fa[2 * i + 1] = p[1];
        }
    };
    auto storesk = [&](int g) {
        #pragma unroll
        for (int i = 0; i < 4; ++i) {
            uint4 wv;
            wv.x = pkbf(fa[2 * i].x,     fa[2 * i].y);
            wv.y = pkbf(fa[2 * i].z,     fa[2 * i].w);
            wv.z = pkbf(fa[2 * i + 1].x, fa[2 * i + 1].y);
            wv.w = pkbf(fa[2 * i + 1].z, fa[2 * i + 1].w);
            if (tail && (k0 + (size_t)(g * 64 + srow + i * 16) >= (size_t)N))
                wv = make_uint4(0, 0, 0, 0);
            *((uint4*)&sK[(srow + 16 * i) * 136 + scol * 8]) = wv;
        }
    };

    loadg(0);
    storesk(0);
    __syncthreads();
    loadg(1);

    for (int round = 0; round < 8; ++round) {
        #pragma unroll
        for (int tt = 0; tt < 4; ++tt) {
            const short* ab = &sK[(tt * 16 + n) * 136 + quad * 8];
            short8 a0 = *(const short8*)(ab);
            short8 a1 = *(const short8*)(ab + 32);
            short8 a2 = *(const short8*)(ab + 64);
            short8 a3 = *(const short8*)(ab + 96);
            f32x4 c0 = {0.f, 0.f, 0.f, 0.f}, c1 = c0, c2 = c0, c3 = c0;
            c0 = MFMA16(a0, bq[0][0], c0);
            c1 = MFMA16(a0, bq[1][0], c1);
            c2 = MFMA16(a0, bq[2][0], c2);
            c3 = MFMA16(a0, bq[3][0], c3);
            c0 = MFMA16(a1, bq[0][1], c0);
            c1 = MFMA16(a1, bq[1][1], c1);
            c2 = MFMA16(a1, bq[2][1], c2);
            c3 = MFMA16(a1, bq[3][1], c3);
            c0 = MFMA16(a2, bq[0][2], c0);
            c1 = MFMA16(a2, bq[1][2], c1);
            c2 = MFMA16(a2, bq[2][2], c2);
            c3 = MFMA16(a2, bq[3][2], c3);
            c0 = MFMA16(a3, bq[0][3], c0);
            c1 = MFMA16(a3, bq[1][3], c1);
            c2 = MFMA16(a3, bq[2][3], c2);
            c3 = MFMA16(a3, bq[3][3], c3);
            // intra-thread frag maxes (frag f = 4 keys of own quad, query col n)
            float m0 = fmaxf(fmaxf(c0[0], c0[1]), fmaxf(c0[2], c0[3]));
            float m1 = fmaxf(fmaxf(c1[0], c1[1]), fmaxf(c1[2], c1[3]));
            float m2 = fmaxf(fmaxf(c2[0], c2[1]), fmaxf(c2[2], c2[3]));
            float m3 = fmaxf(fmaxf(c3[0], c3[1]), fmaxf(c3[2], c3[3]));
            // XOR-select so v_k = m[k ^ quad]  (8 cndmask)
            float u0 = qb0 ? m1 : m0, u1 = qb0 ? m0 : m1;
            float u2 = qb0 ? m3 : m2, u3 = qb0 ? m2 : m3;
            float v0 = qb1 ? u2 : u0, v1 = qb1 ? u3 : u1;
            float v2 = qb1 ? u0 : u2, v3 = qb1 ? u1 : u3;
            // butterfly: A = frag quad over quads {q,q^2}; B = frag quad^1 over {q,q^2};
            // partner(q^1)'s B is frag quad over {q^1,q^3} -> fin = full 16-key max.
            float A = fmaxf(v0, __shfl_xor(v2, 32, 64));
            float B = fmaxf(v1, __shfl_xor(v3, 32, 64));
            float fin = fmaxf(A, __shfl_xor(B, 16, 64));
            // lane (n,quad) stores chunk-max for local query = w*64 + quad*16 + n
            sC[(w * 64 + quad * 16 + n) * SCST + round * 4 + tt] = (_Float16)fin;
        }
        if (round < 7) {
            __syncthreads();
            storesk(round + 1);
            __syncthreads();
            if (round < 6) loadg(round + 2);
        }
    }

    __syncthreads();
    // Flush: thread t = local query t -> 32 fp16 (64 B) at candT[q][strip*32]
    // plus the strip max -> stripT[q][strip]. sC rows are 88 B (8 B-aligned): s4v reads.
    {
        int q = qsg * 256 + t;
        short* dst = (short*)candT + (size_t)q * NCH2 + strip * 32;
        float mx = -3e38f;
        #pragma unroll
        for (int j = 0; j < 4; ++j) {
            s4v lo = *(const s4v*)(&sC[t * SCST + j * 8]);
            s4v hi = *(const s4v*)(&sC[t * SCST + j * 8 + 4]);
            short8 v;
            v[0] = lo[0]; v[1] = lo[1]; v[2] = lo[2]; v[3] = lo[3];
            v[4] = hi[0]; v[5] = hi[1]; v[6] = hi[2]; v[7] = hi[3];
            *(short8*)(dst + j * 8) = v;
            #pragma unroll
            for (int e = 0; e < 8; ++e) {
                short sv = v[e]; _Float16 hv; __builtin_memcpy(&hv, &sv, 2);
                mx = fmaxf(mx, (float)hv);
            }
        }
        stripT[(size_t)q * NSTRIP + strip] = (_Float16)mx;
    }
}

// ---------------- Kernel C: 2-level threshold + batched exact rescore + outputs ----------------
// One 256-thread block per query.
//   P1: thr = (6th-largest STRIP max) - 2*MARGIN. Validity: >=6 distinct strips each
//       contain a key with approx sim >= S6 -> exact sim >= S6-MARGIN; >=5 survive
//       exclusion, so t5_exact >= S6-MARGIN; any top-5 key k: cmax[chunk(k)] >=
//       sim(k)-MARGIN >= t5-MARGIN >= S6-2*MARGIN = thr.
//   P2a: passing strips (smax >= thr); P2b: read only those strips' 32 chunk maxes
//        from candT (64 B each) -> candidate chunk list. Overflow -> full scan.
//   P3: rescore candidates in parallel, fp32-exact: lane = one key; 16 chunks/round.
//   P4: merge per-thread top-5 -> block top-5 -> softmax/gather/normalize.
__global__ __launch_bounds__(256, 4) void finalize_batch(
    const _Float16* __restrict__ candT, const _Float16* __restrict__ stripT,
    const float* __restrict__ mem, const float* __restrict__ qn,
    const int* __restrict__ index_map, const int* __restrict__ excl,
    float* __restrict__ outR, float* __restrict__ outD, float* __restrict__ outW, int N) {
    const int q = blockIdx.x, t = threadIdx.x;
    const int w = t >> 6, lane = t & 63;

    __shared__ __align__(16) float sQ[D128];
    __shared__ __align__(16) _Float16 sS[NSTRIP];    // 784 B strip maxes
    __shared__ unsigned short sStr[SCAP];
    __shared__ unsigned short sList[CAP];
    __shared__ int sScnt, sSov, sCnt, sOv;
    __shared__ float sThr;
    __shared__ float sMrg[4 * 6];
    __shared__ float sWv[4 * TOPK];
    __shared__ int   sWk[4 * TOPK];
    __shared__ float sW[TOPK];
    __shared__ int   sJ[TOPK];

    if (t < 128) sQ[t] = qn[(size_t)q * D128 + t];
    if (t == 0) { sScnt = 0; sSov = 0; sCnt = 0; sOv = 0; }
    if (t < NSTRIP / 8)
        *(short8*)(&sS[t * 8]) =
            *(const short8*)((const short*)stripT + (size_t)q * NSTRIP + t * 8);
    __syncthreads();

    // ---- P1: per-thread top-6 over strided strip maxes, then wave+block merge ----
    float pv[6];
    #pragma unroll
    for (int i = 0; i < 6; ++i) pv[i] = -3e38f;
    for (int i = t; i < NSTRIP; i += 256) {
        float v = (float)sS[i];
        if (v > pv[5]) insertv<6>(pv, v);
    }
    #pragma unroll
    for (int r = 0; r < 6; ++r) {
        float bv = pv[0];
        #pragma unroll
        for (int off = 32; off > 0; off >>= 1) bv = fmaxf(bv, __shfl_xor(bv, off, 64));
        int ml = (pv[0] == bv) ? lane : 64;
        #pragma unroll
        for (int off = 32; off > 0; off >>= 1) ml = min(ml, __shfl_xor(ml, off, 64));
        if (lane == ml) {
            #pragma unroll
            for (int i = 0; i < 5; ++i) pv[i] = pv[i + 1];
            pv[5] = -3e38f;
        }
        if (lane == 0) sMrg[w * 6 + r] = bv;
    }
    __syncthreads();
    if (t == 0) {
        float b6[6];
        #pragma unroll
        for (int i = 0; i < 6; ++i) b6[i] = -3e38f;
        for (int j = 0; j < 24; ++j) {
            float v = sMrg[j];
            if (v > b6[5]) insertv<6>(b6, v);
        }
        sThr = b6[5] - 2.0f * MARGIN;
    }
    __syncthreads();

    // ---- P2a: passing strips ----
    const float thr = sThr;
    for (int i = t; i < NSTRIP; i += 256) {
        if ((float)sS[i] >= thr) {
            int p = atomicAdd(&sScnt, 1);
            if (p < SCAP) sStr[p] = (unsigned short)i; else sSov = 1;
        }
    }
    __syncthreads();
    const int scnt = min(sScnt, SCAP);

    // ---- P2b: candidate chunks from passing strips' chunk-max rows ----
    if (!sSov) {
        for (int base = 0; base < scnt; base += 8) {
            int si = base + (t >> 5);
            if (si < scnt) {
                int ch = (int)sStr[si] * 32 + (t & 31);
                float v = (float)candT[(size_t)q * NCH2 + ch];
                if (v >= thr) {
                    int p = atomicAdd(&sCnt, 1);
                    if (p < CAP) sList[p] = (unsigned short)ch; else sOv = 1;
                }
            }
        }
    }
    __syncthreads();
    const int ov = (sSov || sOv) ? 1 : 0;
    const int cnt = ov ? NCH2 : min(sCnt, CAP);

    // ---- P3: batched fp32-exact rescore ----
    const int exq = excl[q];
    float tv[TOPK]; int ti[TOPK];
    #pragma unroll
    for (int i = 0; i < TOPK; ++i) { tv[i] = -3e38f; ti[i] = -1; }
    const int rounds = (cnt + 15) >> 4;
    for (int r = 0; r < rounds; ++r) {
        int slot = r * 16 + (t >> 4);
        int ch = (slot < cnt) ? (ov ? slot : (int)sList[slot]) : -1;
        int key = ch * 16 + (t & 15);
        float v = -3e38f;
        if (ch >= 0 && key < N && index_map[key] != exq) {
            const float4* mr = (const float4*)(mem + (size_t)key * D128);
            const float4* qv = (const float4*)sQ;
            float acc = 0.f;
            #pragma unroll
            for (int d = 0; d < 32; ++d) {
                float4 a = mr[d], b = qv[d];
                acc += a.x * b.x + a.y * b.y + a.z * b.z + a.w * b.w;
            }
            v = acc;
        }
        if (v > tv[TOPK - 1]) insertg<TOPK>(tv, ti, v, key);
    }

    // ---- P4: wave extraction (tie-break: smaller key), then block merge ----
    #pragma unroll
    for (int r = 0; r < TOPK; ++r) {
        float bv = tv[0]; int bk = ti[0];
        #pragma unroll
        for (int off = 32; off > 0; off >>= 1) {
            float ovv = __shfl_xor(bv, off, 64);
            int   okk = __shfl_xor(bk, off, 64);
            if (ovv > bv || (ovv == bv && (unsigned)okk < (unsigned)bk)) { bv = ovv; bk = okk; }
        }
        if (tv[0] == bv && ti[0] == bk) {
            #pragma unroll
            for (int i = 0; i < TOPK - 1; ++i) { tv[i] = tv[i + 1]; ti[i] = ti[i + 1]; }
            tv[TOPK - 1] = -3e38f; ti[TOPK - 1] = -1;
        }
        if (lane == 0) { sWv[w * TOPK + r] = bv; sWk[w * TOPK + r] = bk; }
    }
    __syncthreads();
    if (t == 0) {
        float bv[TOPK]; int bi[TOPK];
        #pragma unroll
        for (int i = 0; i < TOPK; ++i) { bv[i] = -3e38f; bi[i] = -1; }
        for (int j = 0; j < 4 * TOPK; ++j) {
            float v = sWv[j];
            if (v > bv[TOPK - 1]) insertg<TOPK>(bv, bi, v, sWk[j]);
        }
        float m = bv[0], ex[TOPK], sum = 0.f;
        #pragma unroll
        for (int k = 0; k < TOPK; ++k) { ex[k] = __expf((bv[k] - m) * 10.0f); sum += ex[k]; }
        float inv = 1.0f / sum;
        #pragma unroll
        for (int k = 0; k < TOPK; ++k) {
            float wk = ex[k] * inv;
            sW[k] = wk; sJ[k] = bi[k];
            outW[(size_t)q * TOPK + k] = wk;
        }
        outD[q] = 1.0f - bv[0];
    }
    __syncthreads();
    if (t < 64) {
        float r0 = 0.f, r1 = 0.f;
        #pragma unroll
        for (int k = 0; k < TOPK; ++k) {
            const float* mr = mem + (size_t)sJ[k] * D128;
            r0 += sW[k] * mr[t];
            r1 += sW[k] * mr[t + 64];
        }
        float ss = r0 * r0 + r1 * r1;
        #pragma unroll
        for (int off = 32; off > 0; off >>= 1) ss += __shfl_xor(ss, off, 64);
        float scale = 1.0f / fmaxf(sqrtf(ss), 1e-12f);
        outR[(size_t)q * D128 + t]      = r0 * scale;
        outR[(size_t)q * D128 + t + 64] = r1 * scale;
    }
}

extern "C" void kernel_launch(void* const* d_in, const int* in_sizes, int n_in,
                              void* d_out, int out_size, void* d_ws, size_t ws_size,
                              hipStream_t stream) {
    const float* query  = (const float*)d_in[0];   // [B,128] fp32
    const float* memory = (const float*)d_in[1];   // [N,128] fp32 (pre-normalized)
    const int* index_map = (const int*)d_in[2];    // [N] int32
    const int* excl      = (const int*)d_in[3];    // [B] int32

    const int B = in_sizes[3];                     // 1024
    const int N = in_sizes[2];                     // 200000

    // Workspace:
    //   qn     fp32 [B*128]        @ 0          (512 KB)
    //   qbf    bf16 [B*128]        @ 524288     (256 KB)
    //   candT  fp16 [B][NCH2]      @ 786432     (25.7 MB)
    //   stripT fp16 [B][NSTRIP]    @ 26476544   (0.8 MB)    total ~27.3 MB
    char* ws = (char*)d_ws;
    float*    qn     = (float*)(ws);
    short*    qbf    = (short*)(ws + 524288);
    _Float16* candT  = (_Float16*)(ws + 786432);
    _Float16* stripT = (_Float16*)(ws + 786432 + 25690112);

    float* outR = (float*)d_out;                   // [B,128]
    float* outD = outR + (size_t)B * D128;         // [B]
    float* outW = outD + B;                        // [B,5]

    qnorm_kernel<<<B, 64, 0, stream>>>(query, qn, qbf);
    simtopk_max<<<NSTRIP * 4, 256, 0, stream>>>(qbf, memory, candT, stripT, N);
    finalize_batch<<<B, 256, 0, stream>>>(candT, stripT, memory, qn, index_map, excl,
                                          outR, outD, outW, N);
}

// Round 4
// 247.038 us; speedup vs baseline: 1.6717x; 1.6717x over previous
//
#include <hip/hip_runtime.h>
#include <hip/hip_bf16.h>
#include <math.h>

// Shapes fixed by setup_inputs: B=1024, N=200000, D=128, K=5
#define D128 128
#define TOPK 5
#define NP 200704        // N padded to 64
#define NCH2 12544       // NP/16 : 16-key chunks
#define NSTRIP 392       // NP/512 strips (pass-A block x-dim)
#define MARGIN 0.008f    // bf16-sim (<=3.9e-3) + fp16-storage (<=4.9e-4) + slack
#define CAP 1024         // candidate-chunk capacity per query (overflow -> full scan)
#define SCAP 96          // candidate-strip capacity per query (overflow -> full scan)
#define SCST 44          // sC row stride in shorts (22 dwords, gcd(22,32)=2: conflict-free b16)

typedef __attribute__((ext_vector_type(8))) short short8;   // 8 bf16 = 4 VGPR
typedef __attribute__((ext_vector_type(4))) short s4v;      // 4 shorts = 8 B
typedef __attribute__((ext_vector_type(4))) float f32x4;    // MFMA acc

__device__ __forceinline__ short f2bf(float f) {
    union { float f; unsigned u; } c; c.f = f;
    unsigned u = c.u + 0x7FFFu + ((c.u >> 16) & 1u);
    return (short)(u >> 16);
}

// packed fp32x2 -> bf16x2 (RNE); compiler emits v_cvt_pk_bf16_f32
__device__ __forceinline__ unsigned pkbf(float x, float y) {
    __hip_bfloat162 h = __float22bfloat162_rn(make_float2(x, y));
    unsigned u; __builtin_memcpy(&u, &h, 4);
    return u;
}

// Guarded branch-free descending insert (val+idx). Precondition: nv > v[NN-1].
template <int NN>
__device__ __forceinline__ void insertg(float (&v)[NN], int (&x)[NN], float nv, int nj) {
    bool g[NN];
    #pragma unroll
    for (int i = 0; i < NN; ++i) g[i] = nv > v[i];
    #pragma unroll
    for (int i = NN - 1; i > 0; --i) {
        v[i] = g[i - 1] ? v[i - 1] : (g[i] ? nv : v[i]);
        x[i] = g[i - 1] ? x[i - 1] : (g[i] ? nj : x[i]);
    }
    v[0] = g[0] ? nv : v[0];
    x[0] = g[0] ? nj : x[0];
}
// Values-only variant. Precondition: nv > v[NN-1].
template <int NN>
__device__ __forceinline__ void insertv(float (&v)[NN], float nv) {
    bool g[NN];
    #pragma unroll
    for (int i = 0; i < NN; ++i) g[i] = nv > v[i];
    #pragma unroll
    for (int i = NN - 1; i > 0; --i)
        v[i] = g[i - 1] ? v[i - 1] : (g[i] ? nv : v[i]);
    v[0] = g[0] ? nv : v[0];
}

// ---------------- Kernel A: normalize queries -> fp32 qn + bf16 qbf ----------------
__global__ void qnorm_kernel(const float* __restrict__ q, float* __restrict__ qn,
                             short* __restrict__ qbf) {
    int b = blockIdx.x, t = threadIdx.x;   // 64 threads
    float v0 = q[(size_t)b * D128 + t];
    float v1 = q[(size_t)b * D128 + t + 64];
    float ss = v0 * v0 + v1 * v1;
    #pragma unroll
    for (int off = 32; off > 0; off >>= 1) ss += __shfl_xor(ss, off, 64);
    float scale = 1.0f / fmaxf(sqrtf(ss), 1e-12f);
    float a0 = v0 * scale, a1 = v1 * scale;
    qn[(size_t)b * D128 + t] = a0;
    qn[(size_t)b * D128 + t + 64] = a1;
    qbf[(size_t)b * D128 + t] = f2bf(a0);
    qbf[(size_t)b * D128 + t + 64] = f2bf(a1);
}

#define MFMA16(a, b, c) __builtin_amdgcn_mfma_f32_16x16x32_bf16(a, b, c, 0, 0, 0)

// ---------------- Kernel B: MFMA sweep (fused fp32->bf16 staging) ----------------
// 1D grid of 1568 blocks, XCD-swizzled: strip = (b&7)+8*(b>>5), qsg = (b>>3)&3.
// The 4 qsg-blocks of one strip get consecutive dispatch slots on the SAME XCD
// (ids differ by 8 -> same XCD under round-robin), so 3 of 4 strip reads are L2 hits.
// Block = 4 waves x 64 queries = 256 queries x one 512-key strip (8 rounds of 64 keys,
// each round = 4 MFMA tiles = 4 chunks). Reads fp32 memory directly: register-prefetch
// pipeline (distance 2) holds 8 float4, converts to bf16 at LDS-write time.
// NOTE: min-waves MUST stay 3 — (256,4) halves the arch-VGPR budget and spills
// bq[4][4]+fa[8] to scratch (R3: +540 MB HBM traffic, 94->250 us).
__global__ __launch_bounds__(256, 3) void simtopk_max(
    const short* __restrict__ qbf, const float* __restrict__ mem,
    _Float16* __restrict__ candT, _Float16* __restrict__ stripT, int N) {
    __shared__ short sK[64 * 136];        // 17.4 KB key tile (272B stride)
    __shared__ _Float16 sC[256 * SCST];   // 22.5 KB chunk-max tile (32 used of 44)
    const int b = blockIdx.x;
    const int strip = (b & 7) + ((b >> 5) << 3);   // 0..391
    const int qsg = (b >> 3) & 3;                  // 0..3
    const int t = threadIdx.x, w = t >> 6, lane = t & 63;
    const int n = lane & 15, quad = lane >> 4;
    const bool qb0 = (quad & 1) != 0, qb1 = (quad & 2) != 0;
    const int qbase = qsg * 256 + w * 64;

    // Resident B-frags: 4 q-tiles x 4 K-steps (64 VGPR)
    short8 bq[4][4];
    #pragma unroll
    for (int f = 0; f < 4; ++f) {
        const short* qrow = qbf + (size_t)(qbase + f * 16 + n) * D128 + quad * 8;
        #pragma unroll
        for (int s = 0; s < 4; ++s) bq[f][s] = *(const short8*)(qrow + s * 32);
    }

    const size_t k0 = (size_t)strip * 512;
    const int srow = t >> 4, scol = t & 15;
    const float* gbase = mem + (k0 + srow) * (size_t)D128 + scol * 8;
    const bool tail = (k0 + 512 > (size_t)N);   // strips 390,391 contain padding rows

    float4 fa[8];   // prefetched fp32 group: 4 rows x 8 floats

    auto loadg = [&](int g) {
        const float* base = gbase + (size_t)g * 64 * D128;
        #pragma unroll
        for (int i = 0; i < 4; ++i) {
            const float4* p = (const float4*)(base + (size_t)i * 16 * D128);
            if (tail) {
                size_t key = k0 + (size_t)(g * 64 + srow + i * 16);
                if (key >= (size_t)N) p = (const float4*)mem;   // safe dummy row
            }
            fa[2 * i]     = p[0];
            fa[2 * i + 1] = p[1];
        }
    };
    auto storesk = [&](int g) {
        #pragma unroll
        for (int i = 0; i < 4; ++i) {
            uint4 wv;
            wv.x = pkbf(fa[2 * i].x,     fa[2 * i].y);
            wv.y = pkbf(fa[2 * i].z,     fa[2 * i].w);
            wv.z = pkbf(fa[2 * i + 1].x, fa[2 * i + 1].y);
            wv.w = pkbf(fa[2 * i + 1].z, fa[2 * i + 1].w);
            if (tail && (k0 + (size_t)(g * 64 + srow + i * 16) >= (size_t)N))
                wv = make_uint4(0, 0, 0, 0);
            *((uint4*)&sK[(srow + 16 * i) * 136 + scol * 8]) = wv;
        }
    };

    loadg(0);
    storesk(0);
    __syncthreads();
    loadg(1);

    for (int round = 0; round < 8; ++round) {
        #pragma unroll
        for (int tt = 0; tt < 4; ++tt) {
            const short* ab = &sK[(tt * 16 + n) * 136 + quad * 8];
            short8 a0 = *(const short8*)(ab);
            short8 a1 = *(const short8*)(ab + 32);
            short8 a2 = *(const short8*)(ab + 64);
            short8 a3 = *(const short8*)(ab + 96);
            f32x4 c0 = {0.f, 0.f, 0.f, 0.f}, c1 = c0, c2 = c0, c3 = c0;
            c0 = MFMA16(a0, bq[0][0], c0);
            c1 = MFMA16(a0, bq[1][0], c1);
            c2 = MFMA16(a0, bq[2][0], c2);
            c3 = MFMA16(a0, bq[3][0], c3);
            c0 = MFMA16(a1, bq[0][1], c0);
            c1 = MFMA16(a1, bq[1][1], c1);
            c2 = MFMA16(a1, bq[2][1], c2);
            c3 = MFMA16(a1, bq[3][1], c3);
            c0 = MFMA16(a2, bq[0][2], c0);
            c1 = MFMA16(a2, bq[1][2], c1);
            c2 = MFMA16(a2, bq[2][2], c2);
            c3 = MFMA16(a2, bq[3][2], c3);
            c0 = MFMA16(a3, bq[0][3], c0);
            c1 = MFMA16(a3, bq[1][3], c1);
            c2 = MFMA16(a3, bq[2][3], c2);
            c3 = MFMA16(a3, bq[3][3], c3);
            // intra-thread frag maxes (frag f = 4 keys of own quad, query col n)
            float m0 = fmaxf(fmaxf(c0[0], c0[1]), fmaxf(c0[2], c0[3]));
            float m1 = fmaxf(fmaxf(c1[0], c1[1]), fmaxf(c1[2], c1[3]));
            float m2 = fmaxf(fmaxf(c2[0], c2[1]), fmaxf(c2[2], c2[3]));
            float m3 = fmaxf(fmaxf(c3[0], c3[1]), fmaxf(c3[2], c3[3]));
            // XOR-select so v_k = m[k ^ quad]  (8 cndmask)
            float u0 = qb0 ? m1 : m0, u1 = qb0 ? m0 : m1;
            float u2 = qb0 ? m3 : m2, u3 = qb0 ? m2 : m3;
            float v0 = qb1 ? u2 : u0, v1 = qb1 ? u3 : u1;
            float v2 = qb1 ? u0 : u2, v3 = qb1 ? u1 : u3;
            // butterfly: A = frag quad over quads {q,q^2}; B = frag quad^1 over {q,q^2};
            // partner(q^1)'s B is frag quad over {q^1,q^3} -> fin = full 16-key max.
            float A = fmaxf(v0, __shfl_xor(v2, 32, 64));
            float B = fmaxf(v1, __shfl_xor(v3, 32, 64));
            float fin = fmaxf(A, __shfl_xor(B, 16, 64));
            // lane (n,quad) stores chunk-max for local query = w*64 + quad*16 + n
            sC[(w * 64 + quad * 16 + n) * SCST + round * 4 + tt] = (_Float16)fin;
        }
        if (round < 7) {
            __syncthreads();
            storesk(round + 1);
            __syncthreads();
            if (round < 6) loadg(round + 2);
        }
    }

    __syncthreads();
    // Flush: thread t = local query t -> 32 fp16 (64 B) at candT[q][strip*32]
    // plus the strip max -> stripT[q][strip]. sC rows are 88 B (8 B-aligned): s4v reads.
    {
        int q = qsg * 256 + t;
        short* dst = (short*)candT + (size_t)q * NCH2 + strip * 32;
        float mx = -3e38f;
        #pragma unroll
        for (int j = 0; j < 4; ++j) {
            s4v lo = *(const s4v*)(&sC[t * SCST + j * 8]);
            s4v hi = *(const s4v*)(&sC[t * SCST + j * 8 + 4]);
            short8 v;
            v[0] = lo[0]; v[1] = lo[1]; v[2] = lo[2]; v[3] = lo[3];
            v[4] = hi[0]; v[5] = hi[1]; v[6] = hi[2]; v[7] = hi[3];
            *(short8*)(dst + j * 8) = v;
            #pragma unroll
            for (int e = 0; e < 8; ++e) {
                short sv = v[e]; _Float16 hv; __builtin_memcpy(&hv, &sv, 2);
                mx = fmaxf(mx, (float)hv);
            }
        }
        stripT[(size_t)q * NSTRIP + strip] = (_Float16)mx;
    }
}

// ---------------- Kernel C: 2-level threshold + batched exact rescore + outputs ----------------
// One 256-thread block per query.
//   P1: thr = (6th-largest STRIP max) - 2*MARGIN. Validity: >=6 distinct strips each
//       contain a key with approx sim >= S6 -> exact sim >= S6-MARGIN; >=5 survive
//       exclusion, so t5_exact >= S6-MARGIN; any top-5 key k: cmax[chunk(k)] >=
//       sim(k)-MARGIN >= t5-MARGIN >= S6-2*MARGIN = thr.
//   P2a: passing strips (smax >= thr); P2b: read only those strips' 32 chunk maxes
//        from candT (64 B each) -> candidate chunk list. Overflow -> full scan.
//   P3: rescore candidates in parallel, fp32-exact: lane = one key; 16 chunks/round.
//   P4: merge per-thread top-5 -> block top-5 -> softmax/gather/normalize.
__global__ __launch_bounds__(256, 4) void finalize_batch(
    const _Float16* __restrict__ candT, const _Float16* __restrict__ stripT,
    const float* __restrict__ mem, const float* __restrict__ qn,
    const int* __restrict__ index_map, const int* __restrict__ excl,
    float* __restrict__ outR, float* __restrict__ outD, float* __restrict__ outW, int N) {
    const int q = blockIdx.x, t = threadIdx.x;
    const int w = t >> 6, lane = t & 63;

    __shared__ __align__(16) float sQ[D128];
    __shared__ __align__(16) _Float16 sS[NSTRIP];    // 784 B strip maxes
    __shared__ unsigned short sStr[SCAP];
    __shared__ unsigned short sList[CAP];
    __shared__ int sScnt, sSov, sCnt, sOv;
    __shared__ float sThr;
    __shared__ float sMrg[4 * 6];
    __shared__ float sWv[4 * TOPK];
    __shared__ int   sWk[4 * TOPK];
    __shared__ float sW[TOPK];
    __shared__ int   sJ[TOPK];

    if (t < 128) sQ[t] = qn[(size_t)q * D128 + t];
    if (t == 0) { sScnt = 0; sSov = 0; sCnt = 0; sOv = 0; }
    if (t < NSTRIP / 8)
        *(short8*)(&sS[t * 8]) =
            *(const short8*)((const short*)stripT + (size_t)q * NSTRIP + t * 8);
    __syncthreads();

    // ---- P1: per-thread top-6 over strided strip maxes, then wave+block merge ----
    float pv[6];
    #pragma unroll
    for (int i = 0; i < 6; ++i) pv[i] = -3e38f;
    for (int i = t; i < NSTRIP; i += 256) {
        float v = (float)sS[i];
        if (v > pv[5]) insertv<6>(pv, v);
    }
    #pragma unroll
    for (int r = 0; r < 6; ++r) {
        float bv = pv[0];
        #pragma unroll
        for (int off = 32; off > 0; off >>= 1) bv = fmaxf(bv, __shfl_xor(bv, off, 64));
        int ml = (pv[0] == bv) ? lane : 64;
        #pragma unroll
        for (int off = 32; off > 0; off >>= 1) ml = min(ml, __shfl_xor(ml, off, 64));
        if (lane == ml) {
            #pragma unroll
            for (int i = 0; i < 5; ++i) pv[i] = pv[i + 1];
            pv[5] = -3e38f;
        }
        if (lane == 0) sMrg[w * 6 + r] = bv;
    }
    __syncthreads();
    if (t == 0) {
        float b6[6];
        #pragma unroll
        for (int i = 0; i < 6; ++i) b6[i] = -3e38f;
        for (int j = 0; j < 24; ++j) {
            float v = sMrg[j];
            if (v > b6[5]) insertv<6>(b6, v);
        }
        sThr = b6[5] - 2.0f * MARGIN;
    }
    __syncthreads();

    // ---- P2a: passing strips ----
    const float thr = sThr;
    for (int i = t; i < NSTRIP; i += 256) {
        if ((float)sS[i] >= thr) {
            int p = atomicAdd(&sScnt, 1);
            if (p < SCAP) sStr[p] = (unsigned short)i; else sSov = 1;
        }
    }
    __syncthreads();
    const int scnt = min(sScnt, SCAP);

    // ---- P2b: candidate chunks from passing strips' chunk-max rows ----
    if (!sSov) {
        for (int base = 0; base < scnt; base += 8) {
            int si = base + (t >> 5);
            if (si < scnt) {
                int ch = (int)sStr[si] * 32 + (t & 31);
                float v = (float)candT[(size_t)q * NCH2 + ch];
                if (v >= thr) {
                    int p = atomicAdd(&sCnt, 1);
                    if (p < CAP) sList[p] = (unsigned short)ch; else sOv = 1;
                }
            }
        }
    }
    __syncthreads();
    const int ov = (sSov || sOv) ? 1 : 0;
    const int cnt = ov ? NCH2 : min(sCnt, CAP);

    // ---- P3: batched fp32-exact rescore ----
    const int exq = excl[q];
    float tv[TOPK]; int ti[TOPK];
    #pragma unroll
    for (int i = 0; i < TOPK; ++i) { tv[i] = -3e38f; ti[i] = -1; }
    const int rounds = (cnt + 15) >> 4;
    for (int r = 0; r < rounds; ++r) {
        int slot = r * 16 + (t >> 4);
        int ch = (slot < cnt) ? (ov ? slot : (int)sList[slot]) : -1;
        int key = ch * 16 + (t & 15);
        float v = -3e38f;
        if (ch >= 0 && key < N && index_map[key] != exq) {
            const float4* mr = (const float4*)(mem + (size_t)key * D128);
            const float4* qv = (const float4*)sQ;
            float acc = 0.f;
            #pragma unroll
            for (int d = 0; d < 32; ++d) {
                float4 a = mr[d], b = qv[d];
                acc += a.x * b.x + a.y * b.y + a.z * b.z + a.w * b.w;
            }
            v = acc;
        }
        if (v > tv[TOPK - 1]) insertg<TOPK>(tv, ti, v, key);
    }

    // ---- P4: wave extraction (tie-break: smaller key), then block merge ----
    #pragma unroll
    for (int r = 0; r < TOPK; ++r) {
        float bv = tv[0]; int bk = ti[0];
        #pragma unroll
        for (int off = 32; off > 0; off >>= 1) {
            float ovv = __shfl_xor(bv, off, 64);
            int   okk = __shfl_xor(bk, off, 64);
            if (ovv > bv || (ovv == bv && (unsigned)okk < (unsigned)bk)) { bv = ovv; bk = okk; }
        }
        if (tv[0] == bv && ti[0] == bk) {
            #pragma unroll
            for (int i = 0; i < TOPK - 1; ++i) { tv[i] = tv[i + 1]; ti[i] = ti[i + 1]; }
            tv[TOPK - 1] = -3e38f; ti[TOPK - 1] = -1;
        }
        if (lane == 0) { sWv[w * TOPK + r] = bv; sWk[w * TOPK + r] = bk; }
    }
    __syncthreads();
    if (t == 0) {
        float bv[TOPK]; int bi[TOPK];
        #pragma unroll
        for (int i = 0; i < TOPK; ++i) { bv[i] = -3e38f; bi[i] = -1; }
        for (int j = 0; j < 4 * TOPK; ++j) {
            float v = sWv[j];
            if (v > bv[TOPK - 1]) insertg<TOPK>(bv, bi, v, sWk[j]);
        }
        float m = bv[0], ex[TOPK], sum = 0.f;
        #pragma unroll
        for (int k = 0; k < TOPK; ++k) { ex[k] = __expf((bv[k] - m) * 10.0f); sum += ex[k]; }
        float inv = 1.0f / sum;
        #pragma unroll
        for (int k = 0; k < TOPK; ++k) {
            float wk = ex[k] * inv;
            sW[k] = wk; sJ[k] = bi[k];
            outW[(size_t)q * TOPK + k] = wk;
        }
        outD[q] = 1.0f - bv[0];
    }
    __syncthreads();
    if (t < 64) {
        float r0 = 0.f, r1 = 0.f;
        #pragma unroll
        for (int k = 0; k < TOPK; ++k) {
            const float* mr = mem + (size_t)sJ[k] * D128;
            r0 += sW[k] * mr[t];
            r1 += sW[k] * mr[t + 64];
        }
        float ss = r0 * r0 + r1 * r1;
        #pragma unroll
        for (int off = 32; off > 0; off >>= 1) ss += __shfl_xor(ss, off, 64);
        float scale = 1.0f / fmaxf(sqrtf(ss), 1e-12f);
        outR[(size_t)q * D128 + t]      = r0 * scale;
        outR[(size_t)q * D128 + t + 64] = r1 * scale;
    }
}

extern "C" void kernel_launch(void* const* d_in, const int* in_sizes, int n_in,
                              void* d_out, int out_size, void* d_ws, size_t ws_size,
                              hipStream_t stream) {
    const float* query  = (const float*)d_in[0];   // [B,128] fp32
    const float* memory = (const float*)d_in[1];   // [N,128] fp32 (pre-normalized)
    const int* index_map = (const int*)d_in[2];    // [N] int32
    const int* excl      = (const int*)d_in[3];    // [B] int32

    const int B = in_sizes[3];                     // 1024
    const int N = in_sizes[2];                     // 200000

    // Workspace:
    //   qn     fp32 [B*128]        @ 0          (512 KB)
    //   qbf    bf16 [B*128]        @ 524288     (256 KB)
    //   candT  fp16 [B][NCH2]      @ 786432     (25.7 MB)
    //   stripT fp16 [B][NSTRIP]    @ 26476544   (0.8 MB)    total ~27.3 MB
    char* ws = (char*)d_ws;
    float*    qn     = (float*)(ws);
    short*    qbf    = (short*)(ws + 524288);
    _Float16* candT  = (_Float16*)(ws + 786432);
    _Float16* stripT = (_Float16*)(ws + 786432 + 25690112);

    float* outR = (float*)d_out;                   // [B,128]
    float* outD = outR + (size_t)B * D128;         // [B]
    float* outW = outD + B;                        // [B,5]

    qnorm_kernel<<<B, 64, 0, stream>>>(query, qn, qbf);
    simtopk_max<<<NSTRIP * 4, 256, 0, stream>>>(qbf, memory, candT, stripT, N);
    finalize_batch<<<B, 256, 0, stream>>>(candT, stripT, memory, qn, index_map, excl,
                                          outR, outD, outW, N);
}